// Round 11
// baseline (178.424 us; speedup 1.0000x reference)
//
#include <hip/hip_runtime.h>
#include <hip/hip_bf16.h>

// Problem constants (fixed by the reference setup)
#define N_ROWS   500000
#define NR1      25        // nr + 1
#define NGROUPS  20000     // N_ROWS / NR1
#define KCTX     20        // K context indices
#define H        128
#define NODES    10000
#define IDX_COLS 23        // 3 + K

typedef __attribute__((ext_vector_type(8))) short short8;   // 8 bf16 = 4 VGPRs
typedef __attribute__((ext_vector_type(4))) float f32x4;    // MFMA C/D

// pack two floats -> two bf16 (RNE) as a 32-bit word
__device__ __forceinline__ unsigned pkbf(float lo, float hi) {
  __hip_bfloat162 h = __float22bfloat162_rn(make_float2(lo, hi));
  union { __hip_bfloat162 h; unsigned u; } c; c.h = h;
  return c.u;
}
// bf16-pair word -> two floats (1 VALU each)
__device__ __forceinline__ float lo2f(unsigned u) {
  union { unsigned u; float f; } c; c.u = u << 16; return c.f;
}
__device__ __forceinline__ float hi2f(unsigned u) {
  union { unsigned u; float f; } c; c.u = u & 0xffff0000u; return c.f;
}
// nontemporal 16B gather (bypass L1 allocation — probe the MSHR wall)
__device__ __forceinline__ short8 ntload(const short8* p) {
  return __builtin_nontemporal_load(p);
}

// ---------------------------------------------------------------------------
// Kernel X: xh = bf16 copy of x (2.56 MB). The k_pre ctx-mean gathers
//  then touch 256B rows instead of 512B -> halves that scattered-fill traffic.
// ---------------------------------------------------------------------------
#define XH_BLOCKS 640
__global__ __launch_bounds__(256) void k_copyx(
    const float* __restrict__ x, unsigned* __restrict__ xh) {
  const int n = NODES * H / 2;               // 640K u32 outputs
  for (int i = blockIdx.x * 256 + threadIdx.x; i < n; i += XH_BLOCKS * 256) {
    const float2 v = ((const float2*)x)[i];
    xh[i] = pkbf(v.x, v.y);
  }
}

// ---------------------------------------------------------------------------
// Kernel PRE (v12): = v11, but ctx means gather from xh (bf16) not x (f32).
//   blocks [0,313)      : FAT Pg — means(xh)->LDS once; W13 GEMM ch-split
//   blocks [313,941)    : P1 = x @ W10.T, P2 = x @ W11.T (16 KB)
//   blocks [941,2895)   : idx-pack, coalesced via LDS
//   block  2895         : w2f pack (W2 -> bf16 MFMA-fragment order)
// ---------------------------------------------------------------------------
#define PN 64
#define PBLK      ((NODES + PN - 1) / PN)        // 157
#define B_FAT     ((NGROUPS + 63) / 64)          // 313 fat Pg blocks
#define B_P12     B_FAT                          // 313
#define B_IDX     (B_P12 + 4 * PBLK)             // 941
#define IDX_ROWS  256
#define IDX_BLKS  ((N_ROWS + IDX_ROWS - 1) / IDX_ROWS)   // 1954
#define B_W2FP    (B_IDX + IDX_BLKS)             // 2895
#define PRE_BLOCKS (B_W2FP + 1)                  // 2896

__global__ __launch_bounds__(256) void k_pre(
    const int* __restrict__ indices, const float* __restrict__ x,
    const unsigned* __restrict__ xh,
    const float* __restrict__ W1, const float* __restrict__ b1,
    const float* __restrict__ W2,
    unsigned short* __restrict__ Pb, unsigned short* __restrict__ Pgb,
    unsigned short* __restrict__ w2f, int2* __restrict__ idx2) {
  __shared__ __align__(16) short lds_all[16384];   // 32 KB, aliased per path

  const int tid = threadIdx.x;
  const int bid = blockIdx.x;
  const int lane = tid & 63;
  const int wvid = tid >> 6;
  const int col  = lane & 15;
  const int quad = lane >> 4;

  if (bid >= B_IDX) {
    if (bid == B_W2FP) {
#pragma unroll
      for (int i = 0; i < 4; ++i) {
        const int fi = i * 4 + wvid;         // 0..15
        const int kt = fi >> 2, ct = fi & 3;
        const float* __restrict__ src =
            W2 + (size_t)(ct * 16 + col) * H + kt * 32 + quad * 8;
        const float4 v0 = *(const float4*)src;
        const float4 v1 = *(const float4*)(src + 4);
        union { short8 v; unsigned u[4]; } pk;
        pk.u[0] = pkbf(v0.x, v0.y);
        pk.u[1] = pkbf(v0.z, v0.w);
        pk.u[2] = pkbf(v1.x, v1.y);
        pk.u[3] = pkbf(v1.z, v1.w);
        *(short8*)(w2f + (size_t)(fi * 64 + lane) * 8) = pk.v;
      }
      return;
    }
    // ---- idx-pack, coalesced: dense stream -> LDS -> int2 table ----
    int* ilds = (int*)lds_all;               // up to 5888 ints = 23.5 KB
    const int rbase = (bid - B_IDX) * IDX_ROWS;
    const int nrows = (N_ROWS - rbase < IDX_ROWS) ? (N_ROWS - rbase) : IDX_ROWS;
    const int nints = nrows * IDX_COLS;
    const int* __restrict__ src = indices + (size_t)rbase * IDX_COLS;
    const int n4 = nints >> 2;               // 23552 B block: 16B-aligned
    const int4* __restrict__ src4 = (const int4*)src;
    for (int i = tid; i < n4; i += 256) ((int4*)ilds)[i] = src4[i];
    for (int i = (n4 << 2) + tid; i < nints; i += 256) ilds[i] = src[i];
    __syncthreads();
    for (int r = tid; r < nrows; r += 256)
      idx2[rbase + r] = make_int2(ilds[r * IDX_COLS], ilds[r * IDX_COLS + 1]);
    return;
  }

  if (bid < B_FAT) {
    // ---- FAT Pg block: 64 groups; means once, W13 GEMM in two ch halves ----
    short* w13h = lds_all;             // [64][128] bf16, swizzled (16 KB)
    short* mlds = lds_all + 8192;      // [64][128] bf16 means, swizzled (16 KB)
    const int gbase = bid * 64;

    const int jj = lane;               // u32 index: 2 cols per lane
#pragma unroll
    for (int it = 0; it < 8; ++it) {
      const int ga = gbase + wvid * 16 + it;
      const int gb = ga + 8;
      const int gac = (ga < NGROUPS) ? ga : (NGROUPS - 1);
      const int gbc = (gb < NGROUPS) ? gb : (NGROUPS - 1);
      const int* __restrict__ ra = indices + (size_t)gac * NR1 * IDX_COLS + 3;
      const int* __restrict__ rb = indices + (size_t)gbc * NR1 * IDX_COLS + 3;
      float a0 = 0.f, a1 = 0.f, c0 = 0.f, c1 = 0.f;
      int ca = 0, cb = 0;
#pragma unroll
      for (int c = 0; c < KCTX; ++c) {
        const int ia = ra[c], ib = rb[c];
        const unsigned wa = xh[(size_t)ia * (H / 2) + jj];
        const unsigned wb = xh[(size_t)ib * (H / 2) + jj];
        a0 += lo2f(wa); a1 += hi2f(wa);
        c0 += lo2f(wb); c1 += hi2f(wb);
        ca += (ia > 0) ? 1 : 0; cb += (ib > 0) ? 1 : 0;
      }
      const float rna = 1.f / (float)((ca > 1) ? ca : 1);
      const float rnb = 1.f / (float)((cb > 1) ? cb : 1);
      {
        const int row = wvid * 16 + it;
        const int sb = row * 128 + (((lane >> 2) ^ (row & 7)) << 3) + (lane & 3) * 2;
        *(unsigned*)&mlds[sb] = pkbf(a0 * rna, a1 * rna);
      }
      {
        const int row = wvid * 16 + it + 8;
        const int sb = row * 128 + (((lane >> 2) ^ (row & 7)) << 3) + (lane & 3) * 2;
        *(unsigned*)&mlds[sb] = pkbf(c0 * rnb, c1 * rnb);
      }
    }

    // stage W13 ch=0 -> w13h, swizzled
#pragma unroll
    for (int it = 0; it < 8; ++it) {
      const int f  = it * 256 + tid;   // 0..2047 float4 index
      const int j  = f >> 5;           // 0..63 row
      const int q4 = f & 31;
      const float4 v = *(const float4*)(W1 + (size_t)j * (3 * H) + 2 * H + q4 * 4);
      const int sidx = j * 128 + (((q4 >> 1) ^ (j & 7)) << 3) + (q4 & 1) * 4;
      *(unsigned*)&w13h[sidx]     = pkbf(v.x, v.y);
      *(unsigned*)&w13h[sidx + 2] = pkbf(v.z, v.w);
    }
    __syncthreads();

    short8 Af[4];
    const int arow = wvid * 16 + col;
#pragma unroll
    for (int kt = 0; kt < 4; ++kt)
      Af[kt] = *(const short8*)
          &mlds[arow * 128 + (((kt * 4 + quad) ^ (arow & 7)) << 3)];

    for (int ch = 0; ch < 2; ++ch) {
      if (ch == 1) {
        __syncthreads();   // all waves done reading w13h(ch=0)
#pragma unroll
        for (int it = 0; it < 8; ++it) {
          const int f  = it * 256 + tid;
          const int j  = f >> 5;
          const int q4 = f & 31;
          const float4 v =
              *(const float4*)(W1 + (size_t)(64 + j) * (3 * H) + 2 * H + q4 * 4);
          const int sidx = j * 128 + (((q4 >> 1) ^ (j & 7)) << 3) + (q4 & 1) * 4;
          *(unsigned*)&w13h[sidx]     = pkbf(v.x, v.y);
          *(unsigned*)&w13h[sidx + 2] = pkbf(v.z, v.w);
        }
        __syncthreads();
      }
      f32x4 acc[4];
#pragma unroll
      for (int ct = 0; ct < 4; ++ct) acc[ct] = (f32x4)(0.f);
#pragma unroll
      for (int kt = 0; kt < 4; ++kt) {
#pragma unroll
        for (int ct = 0; ct < 4; ++ct) {
          const int brow = ct * 16 + col;
          const short8 Bf = *(const short8*)
              &w13h[brow * 128 + (((kt * 4 + quad) ^ (brow & 7)) << 3)];
          acc[ct] = __builtin_amdgcn_mfma_f32_16x16x32_bf16(Af[kt], Bf, acc[ct], 0, 0, 0);
        }
      }
      float b1v[4];
#pragma unroll
      for (int ct = 0; ct < 4; ++ct) b1v[ct] = b1[ch * 64 + ct * 16 + col];
#pragma unroll
      for (int reg = 0; reg < 4; ++reg) {
        const int g2 = gbase + wvid * 16 + quad * 4 + reg;
        if (g2 < NGROUPS) {
#pragma unroll
          for (int ct = 0; ct < 4; ++ct) {
            union { unsigned u; unsigned short s[2]; } cc;
            cc.u = pkbf(acc[ct][reg] + b1v[ct], 0.f);
            Pgb[(size_t)g2 * H + ch * 64 + ct * 16 + col] = cc.s[0];
          }
        }
      }
    }
    return;
  }

  // ---- P1/P2 GEMM slices (16 KB LDS) ----
  {
    short* wlds = lds_all;
    const int local = bid - B_P12;
    const int m   = local / (2 * PBLK);      // 0 or 1
    const int sub = local - m * (2 * PBLK);
    const int tbase = (sub >> 1) * PN;
    const int ch    = sub & 1;

#pragma unroll
    for (int it = 0; it < 8; ++it) {
      const int f  = it * 256 + tid;
      const int j  = f >> 5;
      const int q4 = f & 31;
      const float4 v =
          *(const float4*)(W1 + (size_t)(ch * 64 + j) * (3 * H) + m * H + q4 * 4);
      const int sidx = j * 128 + (((q4 >> 1) ^ (j & 7)) << 3) + (q4 & 1) * 4;
      *(unsigned*)&wlds[sidx]     = pkbf(v.x, v.y);
      *(unsigned*)&wlds[sidx + 2] = pkbf(v.z, v.w);
    }
    __syncthreads();

    int node = tbase + wvid * 16 + col;
    if (node > NODES - 1) node = NODES - 1;
    const float4* __restrict__ xr = (const float4*)(x + (size_t)node * H);
    short8 Af[4];
#pragma unroll
    for (int kt = 0; kt < 4; ++kt) {
      const int f4 = kt * 8 + quad * 2;
      const float4 v0 = xr[f4], v1 = xr[f4 + 1];
      union { short8 v; unsigned u[4]; } pk;
      pk.u[0] = pkbf(v0.x, v0.y);
      pk.u[1] = pkbf(v0.z, v0.w);
      pk.u[2] = pkbf(v1.x, v1.y);
      pk.u[3] = pkbf(v1.z, v1.w);
      Af[kt] = pk.v;
    }

    f32x4 acc[4];
#pragma unroll
    for (int ct = 0; ct < 4; ++ct) acc[ct] = (f32x4)(0.f);
#pragma unroll
    for (int kt = 0; kt < 4; ++kt) {
#pragma unroll
      for (int ct = 0; ct < 4; ++ct) {
        const int brow = ct * 16 + col;
        const short8 Bf = *(const short8*)
            &wlds[brow * 128 + (((kt * 4 + quad) ^ (brow & 7)) << 3)];
        acc[ct] = __builtin_amdgcn_mfma_f32_16x16x32_bf16(Af[kt], Bf, acc[ct], 0, 0, 0);
      }
    }

    unsigned short* __restrict__ Pm = Pb + (size_t)m * NODES * H;
#pragma unroll
    for (int reg = 0; reg < 4; ++reg) {
      const int n = tbase + wvid * 16 + quad * 4 + reg;
      if (n < NODES) {
#pragma unroll
        for (int ct = 0; ct < 4; ++ct) {
          union { unsigned u; unsigned short s[2]; } c;
          c.u = pkbf(acc[ct][reg], 0.f);
          Pm[(size_t)n * H + ch * 64 + ct * 16 + col] = c.s[0];
        }
      }
    }
  }
}

// ---------------------------------------------------------------------------
// Kernel C (v20): R7's v17 structure (measured best: 46.8 us) + NONTEMPORAL
//  P1/P2 gathers. R8/R9 showed the scattered-fetch path is pinned at ~1 TB/s
//  regardless of TLP/ILP (Little's law: only ~13 outstanding misses/CU) —
//  consistent with an L1 miss-queue cap. NT loads bypass L1 allocation;
//  if the cap is allocation-side this deepens concurrency. Pg reads stay
//  cached (broadcast-heavy, L1-hits).
// ---------------------------------------------------------------------------
#define RPW 32       // rows per wave
__global__ __launch_bounds__(256, 4) void k_main(
    const int2* __restrict__ idx2,
    const unsigned short* __restrict__ P1b, const unsigned short* __restrict__ P2b,
    const unsigned short* __restrict__ Pgb, const unsigned short* __restrict__ w2f,
    const float* __restrict__ b2, const float* __restrict__ W3,
    const float* __restrict__ b3, float* __restrict__ out) {
  __shared__ __align__(16) short w2s[16 * 64 * 8];   // 16 KB, fragment-ordered

  const int tid  = threadIdx.x;
  const int lane = tid & 63;
  const int wv   = tid >> 6;
  const int col  = lane & 15;
  const int quad = lane >> 4;

  // ---- stage w2f -> LDS (64 B/thread, dense) + barrier at block start ----
  {
    const short8* __restrict__ src = (const short8*)w2f;
    short8* dst = (short8*)w2s;
#pragma unroll
    for (int i = 0; i < 4; ++i) dst[i * 256 + tid] = src[i * 256 + tid];
  }
  __syncthreads();

  const int Rw = (blockIdx.x * 4 + wv) * RPW;        // this wave's 32 rows
  const int r0 = Rw + col, r1 = Rw + 16 + col;
  const int rc0 = (r0 < N_ROWS) ? r0 : (N_ROWS - 1);
  const int rc1 = (r1 < N_ROWS) ? r1 : (N_ROWS - 1);
  const int g0 = rc0 / NR1, g1 = rc1 / NR1;          // magic-mul division

  // ---- ctx gathers (no load dependency -> issue first; cached) ----
  const short8* __restrict__ pc0 = (const short8*)(Pgb + (size_t)g0 * H);
  const short8* __restrict__ pc1 = (const short8*)(Pgb + (size_t)g1 * H);
  short8 uc0[4], uc1[4];
#pragma unroll
  for (int kt = 0; kt < 4; ++kt) {
    uc0[kt] = pc0[kt * 4 + quad];
    uc1[kt] = pc1[kt * 4 + quad];
  }

  // ---- row indices from packed table (8 B/row, sequential, L2/L3-hot) ----
  const int2 iA = idx2[rc0];
  const int2 iB = idx2[rc1];

  // ---- P1/P2 gathers, both groups, all in flight, NONTEMPORAL ----
  const short8* __restrict__ pa0 = (const short8*)(P1b + (size_t)iA.x * H);
  const short8* __restrict__ pb0 = (const short8*)(P2b + (size_t)iA.y * H);
  const short8* __restrict__ pa1 = (const short8*)(P1b + (size_t)iB.x * H);
  const short8* __restrict__ pb1 = (const short8*)(P2b + (size_t)iB.y * H);
  short8 ua0[4], ub0[4], ua1[4], ub1[4];
#pragma unroll
  for (int kt = 0; kt < 4; ++kt) {
    ua0[kt] = ntload(pa0 + kt * 4 + quad);
    ub0[kt] = ntload(pb0 + kt * 4 + quad);
    ua1[kt] = ntload(pa1 + kt * 4 + quad);
    ub1[kt] = ntload(pb1 + kt * 4 + quad);
  }
  __builtin_amdgcn_sched_barrier(0);   // pin: all gathers issued before use

  // ---- epilogue constants (L1-hot) ----
  float b2v[4], w3v[4];
#pragma unroll
  for (int ct = 0; ct < 4; ++ct) {
    b2v[ct] = b2[ct * 16 + col];
    w3v[ct] = W3[ct * 16 + col];
  }
  const float bias3 = b3[0];

  // ---- A-build both groups: relu(P1 + P2 + ctx) -> bf16 fragments ----
  short8 A0[4], A1[4];
#pragma unroll
  for (int kt = 0; kt < 4; ++kt) {
    union { short8 v; unsigned u[4]; } va, vb, vc;
    va.v = ua0[kt]; vb.v = ub0[kt]; vc.v = uc0[kt];
    union { short8 v; unsigned u[4]; } pk;
#pragma unroll
    for (int w = 0; w < 4; ++w) {
      const float hl = fmaxf(lo2f(va.u[w]) + lo2f(vb.u[w]) + lo2f(vc.u[w]), 0.f);
      const float hh = fmaxf(hi2f(va.u[w]) + hi2f(vb.u[w]) + hi2f(vc.u[w]), 0.f);
      pk.u[w] = pkbf(hl, hh);
    }
    A0[kt] = pk.v;
  }
#pragma unroll
  for (int kt = 0; kt < 4; ++kt) {
    union { short8 v; unsigned u[4]; } va, vb, vc;
    va.v = ua1[kt]; vb.v = ub1[kt]; vc.v = uc1[kt];
    union { short8 v; unsigned u[4]; } pk;
#pragma unroll
    for (int w = 0; w < 4; ++w) {
      const float hl = fmaxf(lo2f(va.u[w]) + lo2f(vb.u[w]) + lo2f(vc.u[w]), 0.f);
      const float hh = fmaxf(hi2f(va.u[w]) + hi2f(vb.u[w]) + hi2f(vc.u[w]), 0.f);
      pk.u[w] = pkbf(hl, hh);
    }
    A1[kt] = pk.v;
  }

  // ---- MFMA layer 2: shared B-frags from LDS, both groups ----
  f32x4 acc0[4], acc1[4];
#pragma unroll
  for (int ct = 0; ct < 4; ++ct) { acc0[ct] = (f32x4)(0.f); acc1[ct] = (f32x4)(0.f); }
#pragma unroll
  for (int kt = 0; kt < 4; ++kt) {
#pragma unroll
    for (int ct = 0; ct < 4; ++ct) {
      const short8 Bf = *(const short8*)&w2s[((kt * 4 + ct) * 64 + lane) * 8];
      acc0[ct] = __builtin_amdgcn_mfma_f32_16x16x32_bf16(A0[kt], Bf, acc0[ct], 0, 0, 0);
      acc1[ct] = __builtin_amdgcn_mfma_f32_16x16x32_bf16(A1[kt], Bf, acc1[ct], 0, 0, 0);
    }
  }

  // ---- epilogue: relu(acc+b2) @ W3 + b3, reduce over 16 cols, store ----
#pragma unroll
  for (int grp = 0; grp < 2; ++grp) {
#pragma unroll
    for (int reg = 0; reg < 4; ++reg) {
      float s = 0.f;
#pragma unroll
      for (int ct = 0; ct < 4; ++ct) {
        const float a = (grp == 0) ? acc0[ct][reg] : acc1[ct][reg];
        s += fmaxf(a + b2v[ct], 0.f) * w3v[ct];
      }
      s += __shfl_xor(s, 1);
      s += __shfl_xor(s, 2);
      s += __shfl_xor(s, 4);
      s += __shfl_xor(s, 8);
      if (col == 0) {
        const int row = Rw + grp * 16 + quad * 4 + reg;   // C row = quad*4+reg
        if (row < N_ROWS) out[row] = s + bias3;
      }
    }
  }
}

// ---------------------------------------------------------------------------
extern "C" void kernel_launch(void* const* d_in, const int* in_sizes, int n_in,
                              void* d_out, int out_size, void* d_ws, size_t ws_size,
                              hipStream_t stream) {
  const int*   indices = (const int*)  d_in[0];
  // d_in[1] = nr (scalar, fixed at 24)
  const float* x  = (const float*)d_in[2];
  const float* W1 = (const float*)d_in[3];
  const float* b1 = (const float*)d_in[4];
  const float* W2 = (const float*)d_in[5];
  const float* b2 = (const float*)d_in[6];
  const float* W3 = (const float*)d_in[7];
  const float* b3 = (const float*)d_in[8];
  float* out = (float*)d_out;

  // Workspace: P1|P2 (bf16, 2.56 MB each) | Pg (bf16, 5.12 MB)
  //            | w2f (16 KB) | idx2 (4 MB) | xh (2.56 MB)  => ~16.9 MB
  unsigned short* Pb  = (unsigned short*)d_ws;
  unsigned short* P1b = Pb;
  unsigned short* P2b = Pb + (size_t)NODES * H;
  unsigned short* Pgb = Pb + (size_t)2 * NODES * H;
  unsigned short* w2f = Pgb + (size_t)NGROUPS * H;
  int2* idx2 = (int2*)(w2f + 16 * 64 * 8);
  unsigned* xh = (unsigned*)(idx2 + N_ROWS);

  k_copyx<<<XH_BLOCKS, 256, 0, stream>>>(x, xh);
  k_pre<<<PRE_BLOCKS, 256, 0, stream>>>(indices, x, xh, W1, b1, W2,
                                        Pb, Pgb, w2f, idx2);
  k_main<<<(N_ROWS + 4 * RPW - 1) / (4 * RPW), 256, 0, stream>>>(
      idx2, P1b, P2b, Pgb, w2f, b2, W3, b3, out);
}

// Round 12
// 162.368 us; speedup vs baseline: 1.0989x; 1.0989x over previous
//
#include <hip/hip_runtime.h>
#include <hip/hip_bf16.h>

// Problem constants (fixed by the reference setup)
#define N_ROWS   500000
#define NR1      25        // nr + 1
#define NGROUPS  20000     // N_ROWS / NR1
#define KCTX     20        // K context indices
#define H        128
#define NODES    10000
#define IDX_COLS 23        // 3 + K

typedef __attribute__((ext_vector_type(8))) short short8;   // 8 bf16 = 4 VGPRs
typedef __attribute__((ext_vector_type(4))) float f32x4;    // MFMA C/D

// pack two floats -> two bf16 (RNE) as a 32-bit word
__device__ __forceinline__ unsigned pkbf(float lo, float hi) {
  __hip_bfloat162 h = __float22bfloat162_rn(make_float2(lo, hi));
  union { __hip_bfloat162 h; unsigned u; } c; c.h = h;
  return c.u;
}
// bf16-pair word -> two floats (1 VALU each)
__device__ __forceinline__ float lo2f(unsigned u) {
  union { unsigned u; float f; } c; c.u = u << 16; return c.f;
}
__device__ __forceinline__ float hi2f(unsigned u) {
  union { unsigned u; float f; } c; c.u = u & 0xffff0000u; return c.f;
}

// ---------------------------------------------------------------------------
// Kernel X: xh = bf16 copy of x (2.56 MB). The k_pre ctx-mean gathers
//  then touch 256B rows instead of 512B -> halves that scattered-fill traffic.
// ---------------------------------------------------------------------------
#define XH_BLOCKS 640
__global__ __launch_bounds__(256) void k_copyx(
    const float* __restrict__ x, unsigned* __restrict__ xh) {
  const int n = NODES * H / 2;               // 640K u32 outputs
  for (int i = blockIdx.x * 256 + threadIdx.x; i < n; i += XH_BLOCKS * 256) {
    const float2 v = ((const float2*)x)[i];
    xh[i] = pkbf(v.x, v.y);
  }
}

// ---------------------------------------------------------------------------
// Kernel PRE (v12): ctx means gather from xh (bf16).
//   blocks [0,313)      : FAT Pg — means(xh)->LDS once; W13 GEMM ch-split
//   blocks [313,941)    : P1 = x @ W10.T, P2 = x @ W11.T (16 KB)
//   blocks [941,2895)   : idx-pack, coalesced via LDS
//   block  2895         : w2f pack (W2 -> bf16 MFMA-fragment order)
// ---------------------------------------------------------------------------
#define PN 64
#define PBLK      ((NODES + PN - 1) / PN)        // 157
#define B_FAT     ((NGROUPS + 63) / 64)          // 313 fat Pg blocks
#define B_P12     B_FAT                          // 313
#define B_IDX     (B_P12 + 4 * PBLK)             // 941
#define IDX_ROWS  256
#define IDX_BLKS  ((N_ROWS + IDX_ROWS - 1) / IDX_ROWS)   // 1954
#define B_W2FP    (B_IDX + IDX_BLKS)             // 2895
#define PRE_BLOCKS (B_W2FP + 1)                  // 2896

__global__ __launch_bounds__(256) void k_pre(
    const int* __restrict__ indices, const float* __restrict__ x,
    const unsigned* __restrict__ xh,
    const float* __restrict__ W1, const float* __restrict__ b1,
    const float* __restrict__ W2,
    unsigned short* __restrict__ Pb, unsigned short* __restrict__ Pgb,
    unsigned short* __restrict__ w2f, int2* __restrict__ idx2) {
  __shared__ __align__(16) short lds_all[16384];   // 32 KB, aliased per path

  const int tid = threadIdx.x;
  const int bid = blockIdx.x;
  const int lane = tid & 63;
  const int wvid = tid >> 6;
  const int col  = lane & 15;
  const int quad = lane >> 4;

  if (bid >= B_IDX) {
    if (bid == B_W2FP) {
#pragma unroll
      for (int i = 0; i < 4; ++i) {
        const int fi = i * 4 + wvid;         // 0..15
        const int kt = fi >> 2, ct = fi & 3;
        const float* __restrict__ src =
            W2 + (size_t)(ct * 16 + col) * H + kt * 32 + quad * 8;
        const float4 v0 = *(const float4*)src;
        const float4 v1 = *(const float4*)(src + 4);
        union { short8 v; unsigned u[4]; } pk;
        pk.u[0] = pkbf(v0.x, v0.y);
        pk.u[1] = pkbf(v0.z, v0.w);
        pk.u[2] = pkbf(v1.x, v1.y);
        pk.u[3] = pkbf(v1.z, v1.w);
        *(short8*)(w2f + (size_t)(fi * 64 + lane) * 8) = pk.v;
      }
      return;
    }
    // ---- idx-pack, coalesced: dense stream -> LDS -> int2 table ----
    int* ilds = (int*)lds_all;               // up to 5888 ints = 23.5 KB
    const int rbase = (bid - B_IDX) * IDX_ROWS;
    const int nrows = (N_ROWS - rbase < IDX_ROWS) ? (N_ROWS - rbase) : IDX_ROWS;
    const int nints = nrows * IDX_COLS;
    const int* __restrict__ src = indices + (size_t)rbase * IDX_COLS;
    const int n4 = nints >> 2;               // 23552 B block: 16B-aligned
    const int4* __restrict__ src4 = (const int4*)src;
    for (int i = tid; i < n4; i += 256) ((int4*)ilds)[i] = src4[i];
    for (int i = (n4 << 2) + tid; i < nints; i += 256) ilds[i] = src[i];
    __syncthreads();
    for (int r = tid; r < nrows; r += 256)
      idx2[rbase + r] = make_int2(ilds[r * IDX_COLS], ilds[r * IDX_COLS + 1]);
    return;
  }

  if (bid < B_FAT) {
    // ---- FAT Pg block: 64 groups; means once, W13 GEMM in two ch halves ----
    short* w13h = lds_all;             // [64][128] bf16, swizzled (16 KB)
    short* mlds = lds_all + 8192;      // [64][128] bf16 means, swizzled (16 KB)
    const int gbase = bid * 64;

    const int jj = lane;               // u32 index: 2 cols per lane
#pragma unroll
    for (int it = 0; it < 8; ++it) {
      const int ga = gbase + wvid * 16 + it;
      const int gb = ga + 8;
      const int gac = (ga < NGROUPS) ? ga : (NGROUPS - 1);
      const int gbc = (gb < NGROUPS) ? gb : (NGROUPS - 1);
      const int* __restrict__ ra = indices + (size_t)gac * NR1 * IDX_COLS + 3;
      const int* __restrict__ rb = indices + (size_t)gbc * NR1 * IDX_COLS + 3;
      float a0 = 0.f, a1 = 0.f, c0 = 0.f, c1 = 0.f;
      int ca = 0, cb = 0;
#pragma unroll
      for (int c = 0; c < KCTX; ++c) {
        const int ia = ra[c], ib = rb[c];
        const unsigned wa = xh[(size_t)ia * (H / 2) + jj];
        const unsigned wb = xh[(size_t)ib * (H / 2) + jj];
        a0 += lo2f(wa); a1 += hi2f(wa);
        c0 += lo2f(wb); c1 += hi2f(wb);
        ca += (ia > 0) ? 1 : 0; cb += (ib > 0) ? 1 : 0;
      }
      const float rna = 1.f / (float)((ca > 1) ? ca : 1);
      const float rnb = 1.f / (float)((cb > 1) ? cb : 1);
      {
        const int row = wvid * 16 + it;
        const int sb = row * 128 + (((lane >> 2) ^ (row & 7)) << 3) + (lane & 3) * 2;
        *(unsigned*)&mlds[sb] = pkbf(a0 * rna, a1 * rna);
      }
      {
        const int row = wvid * 16 + it + 8;
        const int sb = row * 128 + (((lane >> 2) ^ (row & 7)) << 3) + (lane & 3) * 2;
        *(unsigned*)&mlds[sb] = pkbf(c0 * rnb, c1 * rnb);
      }
    }

    // stage W13 ch=0 -> w13h, swizzled
#pragma unroll
    for (int it = 0; it < 8; ++it) {
      const int f  = it * 256 + tid;   // 0..2047 float4 index
      const int j  = f >> 5;           // 0..63 row
      const int q4 = f & 31;
      const float4 v = *(const float4*)(W1 + (size_t)j * (3 * H) + 2 * H + q4 * 4);
      const int sidx = j * 128 + (((q4 >> 1) ^ (j & 7)) << 3) + (q4 & 1) * 4;
      *(unsigned*)&w13h[sidx]     = pkbf(v.x, v.y);
      *(unsigned*)&w13h[sidx + 2] = pkbf(v.z, v.w);
    }
    __syncthreads();

    short8 Af[4];
    const int arow = wvid * 16 + col;
#pragma unroll
    for (int kt = 0; kt < 4; ++kt)
      Af[kt] = *(const short8*)
          &mlds[arow * 128 + (((kt * 4 + quad) ^ (arow & 7)) << 3)];

    for (int ch = 0; ch < 2; ++ch) {
      if (ch == 1) {
        __syncthreads();   // all waves done reading w13h(ch=0)
#pragma unroll
        for (int it = 0; it < 8; ++it) {
          const int f  = it * 256 + tid;
          const int j  = f >> 5;
          const int q4 = f & 31;
          const float4 v =
              *(const float4*)(W1 + (size_t)(64 + j) * (3 * H) + 2 * H + q4 * 4);
          const int sidx = j * 128 + (((q4 >> 1) ^ (j & 7)) << 3) + (q4 & 1) * 4;
          *(unsigned*)&w13h[sidx]     = pkbf(v.x, v.y);
          *(unsigned*)&w13h[sidx + 2] = pkbf(v.z, v.w);
        }
        __syncthreads();
      }
      f32x4 acc[4];
#pragma unroll
      for (int ct = 0; ct < 4; ++ct) acc[ct] = (f32x4)(0.f);
#pragma unroll
      for (int kt = 0; kt < 4; ++kt) {
#pragma unroll
        for (int ct = 0; ct < 4; ++ct) {
          const int brow = ct * 16 + col;
          const short8 Bf = *(const short8*)
              &w13h[brow * 128 + (((kt * 4 + quad) ^ (brow & 7)) << 3)];
          acc[ct] = __builtin_amdgcn_mfma_f32_16x16x32_bf16(Af[kt], Bf, acc[ct], 0, 0, 0);
        }
      }
      float b1v[4];
#pragma unroll
      for (int ct = 0; ct < 4; ++ct) b1v[ct] = b1[ch * 64 + ct * 16 + col];
#pragma unroll
      for (int reg = 0; reg < 4; ++reg) {
        const int g2 = gbase + wvid * 16 + quad * 4 + reg;
        if (g2 < NGROUPS) {
#pragma unroll
          for (int ct = 0; ct < 4; ++ct) {
            union { unsigned u; unsigned short s[2]; } cc;
            cc.u = pkbf(acc[ct][reg] + b1v[ct], 0.f);
            Pgb[(size_t)g2 * H + ch * 64 + ct * 16 + col] = cc.s[0];
          }
        }
      }
    }
    return;
  }

  // ---- P1/P2 GEMM slices (16 KB LDS) ----
  {
    short* wlds = lds_all;
    const int local = bid - B_P12;
    const int m   = local / (2 * PBLK);      // 0 or 1
    const int sub = local - m * (2 * PBLK);
    const int tbase = (sub >> 1) * PN;
    const int ch    = sub & 1;

#pragma unroll
    for (int it = 0; it < 8; ++it) {
      const int f  = it * 256 + tid;
      const int j  = f >> 5;
      const int q4 = f & 31;
      const float4 v =
          *(const float4*)(W1 + (size_t)(ch * 64 + j) * (3 * H) + m * H + q4 * 4);
      const int sidx = j * 128 + (((q4 >> 1) ^ (j & 7)) << 3) + (q4 & 1) * 4;
      *(unsigned*)&wlds[sidx]     = pkbf(v.x, v.y);
      *(unsigned*)&wlds[sidx + 2] = pkbf(v.z, v.w);
    }
    __syncthreads();

    int node = tbase + wvid * 16 + col;
    if (node > NODES - 1) node = NODES - 1;
    const float4* __restrict__ xr = (const float4*)(x + (size_t)node * H);
    short8 Af[4];
#pragma unroll
    for (int kt = 0; kt < 4; ++kt) {
      const int f4 = kt * 8 + quad * 2;
      const float4 v0 = xr[f4], v1 = xr[f4 + 1];
      union { short8 v; unsigned u[4]; } pk;
      pk.u[0] = pkbf(v0.x, v0.y);
      pk.u[1] = pkbf(v0.z, v0.w);
      pk.u[2] = pkbf(v1.x, v1.y);
      pk.u[3] = pkbf(v1.z, v1.w);
      Af[kt] = pk.v;
    }

    f32x4 acc[4];
#pragma unroll
    for (int ct = 0; ct < 4; ++ct) acc[ct] = (f32x4)(0.f);
#pragma unroll
    for (int kt = 0; kt < 4; ++kt) {
#pragma unroll
      for (int ct = 0; ct < 4; ++ct) {
        const int brow = ct * 16 + col;
        const short8 Bf = *(const short8*)
            &wlds[brow * 128 + (((kt * 4 + quad) ^ (brow & 7)) << 3)];
        acc[ct] = __builtin_amdgcn_mfma_f32_16x16x32_bf16(Af[kt], Bf, acc[ct], 0, 0, 0);
      }
    }

    unsigned short* __restrict__ Pm = Pb + (size_t)m * NODES * H;
#pragma unroll
    for (int reg = 0; reg < 4; ++reg) {
      const int n = tbase + wvid * 16 + quad * 4 + reg;
      if (n < NODES) {
#pragma unroll
        for (int ct = 0; ct < 4; ++ct) {
          union { unsigned u; unsigned short s[2]; } c;
          c.u = pkbf(acc[ct][reg], 0.f);
          Pm[(size_t)n * H + ch * 64 + ct * 16 + col] = c.s[0];
        }
      }
    }
  }
}

// ---------------------------------------------------------------------------
// Kernel C (v21): v17 structure, PLAIN cached gathers (NT reverted).
//  R11 A/B verdict: NT P1/P2 loads cost +13 MB FETCH / +10 us — L1/L2
//  allocation of the P-tables is load-bearing (popular node rows re-hit).
//  k_main's dur tracks FETCH_SIZE / ~0.95 TB/s across R5-R11: it is
//  fetch-path-bound; the lever is HBM-missed bytes, not issue concurrency.
// ---------------------------------------------------------------------------
#define RPW 32       // rows per wave
__global__ __launch_bounds__(256, 4) void k_main(
    const int2* __restrict__ idx2,
    const unsigned short* __restrict__ P1b, const unsigned short* __restrict__ P2b,
    const unsigned short* __restrict__ Pgb, const unsigned short* __restrict__ w2f,
    const float* __restrict__ b2, const float* __restrict__ W3,
    const float* __restrict__ b3, float* __restrict__ out) {
  __shared__ __align__(16) short w2s[16 * 64 * 8];   // 16 KB, fragment-ordered

  const int tid  = threadIdx.x;
  const int lane = tid & 63;
  const int wv   = tid >> 6;
  const int col  = lane & 15;
  const int quad = lane >> 4;

  // ---- stage w2f -> LDS (64 B/thread, dense) + barrier at block start ----
  {
    const short8* __restrict__ src = (const short8*)w2f;
    short8* dst = (short8*)w2s;
#pragma unroll
    for (int i = 0; i < 4; ++i) dst[i * 256 + tid] = src[i * 256 + tid];
  }
  __syncthreads();

  const int Rw = (blockIdx.x * 4 + wv) * RPW;        // this wave's 32 rows
  const int r0 = Rw + col, r1 = Rw + 16 + col;
  const int rc0 = (r0 < N_ROWS) ? r0 : (N_ROWS - 1);
  const int rc1 = (r1 < N_ROWS) ? r1 : (N_ROWS - 1);
  const int g0 = rc0 / NR1, g1 = rc1 / NR1;          // magic-mul division

  // ---- ctx gathers (no load dependency -> issue first; cached) ----
  const short8* __restrict__ pc0 = (const short8*)(Pgb + (size_t)g0 * H);
  const short8* __restrict__ pc1 = (const short8*)(Pgb + (size_t)g1 * H);
  short8 uc0[4], uc1[4];
#pragma unroll
  for (int kt = 0; kt < 4; ++kt) {
    uc0[kt] = pc0[kt * 4 + quad];
    uc1[kt] = pc1[kt * 4 + quad];
  }

  // ---- row indices from packed table (8 B/row, sequential, L2/L3-hot) ----
  const int2 iA = idx2[rc0];
  const int2 iB = idx2[rc1];

  // ---- P1/P2 gathers, both groups, all in flight (cached) ----
  const short8* __restrict__ pa0 = (const short8*)(P1b + (size_t)iA.x * H);
  const short8* __restrict__ pb0 = (const short8*)(P2b + (size_t)iA.y * H);
  const short8* __restrict__ pa1 = (const short8*)(P1b + (size_t)iB.x * H);
  const short8* __restrict__ pb1 = (const short8*)(P2b + (size_t)iB.y * H);
  short8 ua0[4], ub0[4], ua1[4], ub1[4];
#pragma unroll
  for (int kt = 0; kt < 4; ++kt) {
    ua0[kt] = pa0[kt * 4 + quad];
    ub0[kt] = pb0[kt * 4 + quad];
    ua1[kt] = pa1[kt * 4 + quad];
    ub1[kt] = pb1[kt * 4 + quad];
  }
  __builtin_amdgcn_sched_barrier(0);   // pin: all gathers issued before use

  // ---- epilogue constants (L1-hot) ----
  float b2v[4], w3v[4];
#pragma unroll
  for (int ct = 0; ct < 4; ++ct) {
    b2v[ct] = b2[ct * 16 + col];
    w3v[ct] = W3[ct * 16 + col];
  }
  const float bias3 = b3[0];

  // ---- A-build both groups: relu(P1 + P2 + ctx) -> bf16 fragments ----
  short8 A0[4], A1[4];
#pragma unroll
  for (int kt = 0; kt < 4; ++kt) {
    union { short8 v; unsigned u[4]; } va, vb, vc;
    va.v = ua0[kt]; vb.v = ub0[kt]; vc.v = uc0[kt];
    union { short8 v; unsigned u[4]; } pk;
#pragma unroll
    for (int w = 0; w < 4; ++w) {
      const float hl = fmaxf(lo2f(va.u[w]) + lo2f(vb.u[w]) + lo2f(vc.u[w]), 0.f);
      const float hh = fmaxf(hi2f(va.u[w]) + hi2f(vb.u[w]) + hi2f(vc.u[w]), 0.f);
      pk.u[w] = pkbf(hl, hh);
    }
    A0[kt] = pk.v;
  }
#pragma unroll
  for (int kt = 0; kt < 4; ++kt) {
    union { short8 v; unsigned u[4]; } va, vb, vc;
    va.v = ua1[kt]; vb.v = ub1[kt]; vc.v = uc1[kt];
    union { short8 v; unsigned u[4]; } pk;
#pragma unroll
    for (int w = 0; w < 4; ++w) {
      const float hl = fmaxf(lo2f(va.u[w]) + lo2f(vb.u[w]) + lo2f(vc.u[w]), 0.f);
      const float hh = fmaxf(hi2f(va.u[w]) + hi2f(vb.u[w]) + hi2f(vc.u[w]), 0.f);
      pk.u[w] = pkbf(hl, hh);
    }
    A1[kt] = pk.v;
  }

  // ---- MFMA layer 2: shared B-frags from LDS, both groups ----
  f32x4 acc0[4], acc1[4];
#pragma unroll
  for (int ct = 0; ct < 4; ++ct) { acc0[ct] = (f32x4)(0.f); acc1[ct] = (f32x4)(0.f); }
#pragma unroll
  for (int kt = 0; kt < 4; ++kt) {
#pragma unroll
    for (int ct = 0; ct < 4; ++ct) {
      const short8 Bf = *(const short8*)&w2s[((kt * 4 + ct) * 64 + lane) * 8];
      acc0[ct] = __builtin_amdgcn_mfma_f32_16x16x32_bf16(A0[kt], Bf, acc0[ct], 0, 0, 0);
      acc1[ct] = __builtin_amdgcn_mfma_f32_16x16x32_bf16(A1[kt], Bf, acc1[ct], 0, 0, 0);
    }
  }

  // ---- epilogue: relu(acc+b2) @ W3 + b3, reduce over 16 cols, store ----
#pragma unroll
  for (int grp = 0; grp < 2; ++grp) {
#pragma unroll
    for (int reg = 0; reg < 4; ++reg) {
      float s = 0.f;
#pragma unroll
      for (int ct = 0; ct < 4; ++ct) {
        const float a = (grp == 0) ? acc0[ct][reg] : acc1[ct][reg];
        s += fmaxf(a + b2v[ct], 0.f) * w3v[ct];
      }
      s += __shfl_xor(s, 1);
      s += __shfl_xor(s, 2);
      s += __shfl_xor(s, 4);
      s += __shfl_xor(s, 8);
      if (col == 0) {
        const int row = Rw + grp * 16 + quad * 4 + reg;   // C row = quad*4+reg
        if (row < N_ROWS) out[row] = s + bias3;
      }
    }
  }
}

// ---------------------------------------------------------------------------
extern "C" void kernel_launch(void* const* d_in, const int* in_sizes, int n_in,
                              void* d_out, int out_size, void* d_ws, size_t ws_size,
                              hipStream_t stream) {
  const int*   indices = (const int*)  d_in[0];
  // d_in[1] = nr (scalar, fixed at 24)
  const float* x  = (const float*)d_in[2];
  const float* W1 = (const float*)d_in[3];
  const float* b1 = (const float*)d_in[4];
  const float* W2 = (const float*)d_in[5];
  const float* b2 = (const float*)d_in[6];
  const float* W3 = (const float*)d_in[7];
  const float* b3 = (const float*)d_in[8];
  float* out = (float*)d_out;

  // Workspace: P1|P2 (bf16, 2.56 MB each) | Pg (bf16, 5.12 MB)
  //            | w2f (16 KB) | idx2 (4 MB) | xh (2.56 MB)  => ~16.9 MB
  unsigned short* Pb  = (unsigned short*)d_ws;
  unsigned short* P1b = Pb;
  unsigned short* P2b = Pb + (size_t)NODES * H;
  unsigned short* Pgb = Pb + (size_t)2 * NODES * H;
  unsigned short* w2f = Pgb + (size_t)NGROUPS * H;
  int2* idx2 = (int2*)(w2f + 16 * 64 * 8);
  unsigned* xh = (unsigned*)(idx2 + N_ROWS);

  k_copyx<<<XH_BLOCKS, 256, 0, stream>>>(x, xh);
  k_pre<<<PRE_BLOCKS, 256, 0, stream>>>(indices, x, xh, W1, b1, W2,
                                        Pb, Pgb, w2f, idx2);
  k_main<<<(N_ROWS + 4 * RPW - 1) / (4 * RPW), 256, 0, stream>>>(
      idx2, P1b, P2b, Pgb, w2f, b2, W3, b3, out);
}